// Round 5
// baseline (592.371 us; speedup 1.0000x reference)
//
#include <hip/hip_runtime.h>

// Problem constants (fixed by reference)
#define NN   20000
#define RR   11
#define BB   8
#define IND  300
#define OUTD 256
#define EE   640000
#define RN   (RR * NN)      // 220000 buckets, key = rel*N + src
#define KP   304            // K padded to 19 * 16 for 32x32x16 MFMA
#define KPU  152            // uints per padded feat2/wt row
#define SBS  316            // sbf ushort stride (632B rows; benign 2-way-ish banks)
#define NSCAN_BLOCKS 215    // ceil(220000 / 1024)
#define FB   2969           // k_prep blocks: feat convert (760000 uint4 / 256)
#define WB   44             // k_prep blocks: wt tiles (11 r x 4 o-tiles)
#define HB   215            // k_prep blocks: hist zero (215*1024)

typedef short bf16x8 __attribute__((ext_vector_type(8)));
typedef float f32x16 __attribute__((ext_vector_type(16)));

union UA { bf16x8 v; uint2 d[2]; };
union UB { bf16x8 v; uint4 q; };

__device__ inline unsigned short f2bf(float f) {
    union { float f; unsigned u; } x;
    x.f = f;
    unsigned u = x.u;
    u += 0x7fffu + ((u >> 16) & 1u);   // round-to-nearest-even
    return (unsigned short)(u >> 16);
}
__device__ inline float bflo(unsigned p) { return __uint_as_float(p << 16); }
__device__ inline float bfhi(unsigned p) { return __uint_as_float(p & 0xFFFF0000u); }
__device__ inline unsigned packbf(float x, float y) {
    return (unsigned)f2bf(x) | ((unsigned)f2bf(y) << 16);
}

// ---- fused prep: feat->bf16 padded rows | wt LDS-transpose tiles | hist zero
__global__ __launch_bounds__(256) void k_prep(const float* __restrict__ feat,
                                              const float* __restrict__ comps,
                                              const float* __restrict__ bases,
                                              unsigned* __restrict__ f2u,
                                              unsigned short* __restrict__ wt,
                                              unsigned* __restrict__ hist) {
    __shared__ unsigned short ld[KP * 65];   // wt tile (k x o), pad 65 -> conflict-free
    const int b = blockIdx.x, tid = threadIdx.x;

    if (b < FB) {
        // f2u[d][0..151] uints (304 bf16, k>=300 zero). 38 uint4 per row.
        const unsigned t = b * 256u + (unsigned)tid;
        if (t < 760000u) {
            const unsigned d = t / 38u, c4 = t - d * 38u, k0 = c4 * 8u;
            const float* fp = feat + (size_t)d * IND + k0;
            float v4 = 0.f, v5 = 0.f, v6 = 0.f, v7 = 0.f;
            const float4 x = *(const float4*)fp;
            if (k0 + 4 < (unsigned)IND) {
                const float4 y = *(const float4*)(fp + 4);
                v4 = y.x; v5 = y.y; v6 = y.z; v7 = y.w;
            }
            uint4 o;
            o.x = packbf(x.x, x.y); o.y = packbf(x.z, x.w);
            o.z = packbf(v4, v5);   o.w = packbf(v6, v7);
            *(uint4*)(f2u + (size_t)t * 4u) = o;
        }
        return;
    }
    if (b < FB + WB) {
        // wt[r][o][k] bf16: coalesced bases reads, LDS transpose, coalesced writes
        const int w  = b - FB;               // 0..43
        const int r  = w >> 2, o0 = (w & 3) * 64;
        const int o4 = tid & 63, kq = tid >> 6;     // kq 0..3
        float cw[BB];
#pragma unroll
        for (int bb = 0; bb < BB; ++bb) cw[bb] = comps[r * BB + bb];
        for (int ks = 0; ks < 76; ++ks) {
            const int k = ks * 4 + kq;
            float acc = 0.f;
            if (k < IND) {
#pragma unroll
                for (int bb = 0; bb < BB; ++bb)
                    acc += cw[bb] * bases[((size_t)bb * IND + k) * OUTD + o0 + o4];
            }
            ld[k * 65 + o4] = f2bf(acc);
        }
        __syncthreads();
        unsigned* wtu = (unsigned*)wt;
        for (int j = tid; j < 64 * KPU; j += 256) {
            const int oo = j / KPU, ku = j - oo * KPU;
            const unsigned lo = ld[(2 * ku) * 65 + oo];
            const unsigned hi = ld[(2 * ku + 1) * 65 + oo];
            wtu[((size_t)(r * OUTD + o0 + oo)) * KPU + ku] = lo | (hi << 16);
        }
        return;
    }
    // hist zero
    const unsigned base = (unsigned)(b - FB - WB) * 1024u + (unsigned)tid;
#pragma unroll
    for (int i = 0; i < 4; ++i) {
        const unsigned idx = base + i * 256u;
        if (idx < RN) hist[idx] = 0u;
    }
}

// ---------------------------------------------------------------- histogram
__global__ __launch_bounds__(256) void k_hist(const int* __restrict__ esrc,
                                              const int* __restrict__ erel,
                                              unsigned* __restrict__ hist) {
    const int e = blockIdx.x * 256 + threadIdx.x;           // exactly 640000
    const unsigned key = (unsigned)erel[e] * NN + (unsigned)esrc[e];
    atomicAdd(&hist[key], 1u);
}

// ------------------------------------------------- scan level 1 (1024/block)
__global__ __launch_bounds__(256) void k_scan1(const unsigned* __restrict__ hist,
                                               unsigned* __restrict__ off,
                                               unsigned* __restrict__ bsum) {
    __shared__ unsigned sc[256];
    const int tid = threadIdx.x;
    const unsigned base = blockIdx.x * 1024u + (unsigned)tid * 4u;
    unsigned v0 = (base + 0 < RN) ? hist[base + 0] : 0u;
    unsigned v1 = (base + 1 < RN) ? hist[base + 1] : 0u;
    unsigned v2 = (base + 2 < RN) ? hist[base + 2] : 0u;
    unsigned v3 = (base + 3 < RN) ? hist[base + 3] : 0u;
    const unsigned s = v0 + v1 + v2 + v3;
    sc[tid] = s;
    __syncthreads();
    for (int d = 1; d < 256; d <<= 1) {
        unsigned t = (tid >= d) ? sc[tid - d] : 0u;
        __syncthreads();
        sc[tid] += t;
        __syncthreads();
    }
    if (tid == 255) bsum[blockIdx.x] = sc[255];
    unsigned run = sc[tid] - s;                              // exclusive
    if (base + 0 < RN) off[base + 0] = run; run += v0;
    if (base + 1 < RN) off[base + 1] = run; run += v1;
    if (base + 2 < RN) off[base + 2] = run; run += v2;
    if (base + 3 < RN) off[base + 3] = run;
}

// ------------- scan levels 2+3 fused: every block re-scans bsum (tiny, L2)
__global__ __launch_bounds__(256) void k_scan23(unsigned* __restrict__ off,
                                                unsigned* __restrict__ off2,
                                                const unsigned* __restrict__ bsum) {
    __shared__ unsigned sb[256];
    const int tid = threadIdx.x;
    if (tid < 64) {
        unsigned v[4]; unsigned tot = 0;
#pragma unroll
        for (int i = 0; i < 4; ++i) {
            const int idx = tid * 4 + i;
            v[i] = (idx < NSCAN_BLOCKS) ? bsum[idx] : 0u;
            tot += v[i];
        }
        unsigned sc = tot;
        for (int d = 1; d < 64; d <<= 1) {
            unsigned t = __shfl_up(sc, d, 64);
            if (tid >= d) sc += t;
        }
        unsigned run = sc - tot;
#pragma unroll
        for (int i = 0; i < 4; ++i) {
            sb[tid * 4 + i] = run;
            run += v[i];
        }
    }
    __syncthreads();
    const unsigned idx = blockIdx.x * 256u + (unsigned)tid;
    if (idx < RN) {
        const unsigned v = off[idx] + sb[idx >> 10];
        off[idx]  = v;
        off2[idx] = v;
    }
    if (idx == 0) off[RN] = EE;
}

// ------------------------------------------------------- counting-sort scatter
__global__ __launch_bounds__(256) void k_scatter(const int* __restrict__ esrc,
                                                 const int* __restrict__ erel,
                                                 const int* __restrict__ edst,
                                                 unsigned* __restrict__ off2,
                                                 unsigned* __restrict__ ssd) {
    const int e = blockIdx.x * 256 + threadIdx.x;           // exactly 640000
    const unsigned key = (unsigned)erel[e] * NN + (unsigned)esrc[e];
    const unsigned p = atomicAdd(&off2[key], 1u);
    ssd[p] = (unsigned)edst[e];                              // dst only; src = bucket
}

// ---------------------------------------------------------------- fused main
// 32 nodes/block, 512 threads (8 waves). Per relation-phase:
//   prologue(r+1): per-group edge-dst register windows (readlane broadcast)
//                  + depth-2 row prefetches for 4 groups (12 loads in flight)
//   mfma(r):       19 k-steps from sbf[buf] (dbl-buffered, 1 barrier/phase)
//   body(r+1):     round-robin 4-group consume with depth-2 prefetch
// No sme staging, no LDS atomics. __launch_bounds__(512,4): 128-VGPR budget
// so the whole pipeline stays in registers (R4's (512,8) forced VGPR=32 and
// serialized everything).
__global__ __launch_bounds__(512, 4) void k_main(const unsigned* __restrict__ f2u,
                                                 const float* __restrict__ bias,
                                                 const unsigned* __restrict__ offs,
                                                 const unsigned* __restrict__ ssd,
                                                 const unsigned short* __restrict__ wt,
                                                 float* __restrict__ out) {
    __shared__ unsigned short sbf[2][32 * SBS];
    __shared__ unsigned soffs[RR * 33];

    const int tid  = threadIdx.x;
    const int wave = tid >> 6;
    const int lane = tid & 63;
    const int row  = lane & 31;
    const int q    = lane >> 5;
    const int n0   = blockIdx.x * 32;
    const int o0   = wave * 32;

    if (tid < RR * 33) {
        const int r = tid / 33, j = tid - r * 33;
        soffs[tid] = offs[r * NN + n0 + j];
    }

    f32x16 acc;
#pragma unroll
    for (int i = 0; i < 16; ++i) acc[i] = 0.f;

    const unsigned cl = (unsigned)(lane < 38 ? lane : 37) * 4u;  // uint col offset

    // pipeline state for next phase's gather
    unsigned gc0[4], gcnt[4], gwin[4];
    uint4    pf0[4], pf1[4];
    unsigned cmax;

    __syncthreads();

    // ---- prologue: load dst windows + depth-2 row prefetches for relation r
#define PROLOGUE(rr)                                                          \
    {                                                                         \
        const unsigned* so = soffs + (rr) * 33 + wave * 4;                    \
        cmax = 0;                                                             \
        _Pragma("unroll")                                                     \
        for (int g = 0; g < 4; ++g) {                                         \
            gc0[g]  = so[g];                                                  \
            gcnt[g] = so[g + 1] - so[g];                                      \
            cmax    = max(cmax, gcnt[g]);                                     \
            gwin[g] = (gc0[g] + (unsigned)lane < so[g + 1])                   \
                          ? ssd[gc0[g] + (unsigned)lane] : 0u;                \
        }                                                                     \
        _Pragma("unroll")                                                     \
        for (int g = 0; g < 4; ++g) {                                         \
            if (gcnt[g] > 0) {                                                \
                const unsigned d = (unsigned)__builtin_amdgcn_readlane((int)gwin[g], 0); \
                pf0[g] = *(const uint4*)(f2u + (size_t)d * KPU + cl);         \
            }                                                                 \
            if (gcnt[g] > 1) {                                                \
                const unsigned d = (unsigned)__builtin_amdgcn_readlane((int)gwin[g], 1); \
                pf1[g] = *(const uint4*)(f2u + (size_t)d * KPU + cl);         \
            }                                                                 \
        }                                                                     \
    }

    // ---- body: round-robin consume (depth-2 per group) -> sbf[bb]
#define BODY(bb)                                                              \
    {                                                                         \
        float fa[4][8];                                                       \
        _Pragma("unroll")                                                     \
        for (int g = 0; g < 4; ++g)                                           \
            _Pragma("unroll")                                                 \
            for (int i = 0; i < 8; ++i) fa[g][i] = 0.f;                       \
        for (unsigned e = 0; e < cmax; e += 2) {                              \
            if (e && !(e & 63u)) { /* window refill: ultra-rare */            \
                _Pragma("unroll")                                             \
                for (int g = 0; g < 4; ++g) {                                 \
                    if (e < gcnt[g]) {                                        \
                        gwin[g] = (gc0[g] + e + (unsigned)lane < gc0[g] + gcnt[g]) \
                                      ? ssd[gc0[g] + e + (unsigned)lane] : 0u; \
                        const unsigned d0 = (unsigned)__builtin_amdgcn_readlane((int)gwin[g], 0); \
                        pf0[g] = *(const uint4*)(f2u + (size_t)d0 * KPU + cl); \
                        if (e + 1 < gcnt[g]) {                                \
                            const unsigned d1 = (unsigned)__builtin_amdgcn_readlane((int)gwin[g], 1); \
                            pf1[g] = *(const uint4*)(f2u + (size_t)d1 * KPU + cl); \
                        }                                                     \
                    }                                                         \
                }                                                             \
            }                                                                 \
            _Pragma("unroll")                                                 \
            for (int g = 0; g < 4; ++g) {                                     \
                if (e < gcnt[g]) {                                            \
                    const uint4 cur = pf0[g];                                 \
                    const unsigned en = e + 2;                                \
                    if (en < gcnt[g] && (en & 63u)) {                         \
                        const unsigned d = (unsigned)__builtin_amdgcn_readlane((int)gwin[g], (int)(en & 63u)); \
                        pf0[g] = *(const uint4*)(f2u + (size_t)d * KPU + cl); \
                    }                                                         \
                    fa[g][0] += bflo(cur.x); fa[g][1] += bfhi(cur.x);         \
                    fa[g][2] += bflo(cur.y); fa[g][3] += bfhi(cur.y);         \
                    fa[g][4] += bflo(cur.z); fa[g][5] += bfhi(cur.z);         \
                    fa[g][6] += bflo(cur.w); fa[g][7] += bfhi(cur.w);         \
                }                                                             \
            }                                                                 \
            _Pragma("unroll")                                                 \
            for (int g = 0; g < 4; ++g) {                                     \
                if (e + 1 < gcnt[g]) {                                        \
                    const uint4 cur = pf1[g];                                 \
                    const unsigned en = e + 3;                                \
                    if (en < gcnt[g] && (en & 63u)) {                         \
                        const unsigned d = (unsigned)__builtin_amdgcn_readlane((int)gwin[g], (int)(en & 63u)); \
                        pf1[g] = *(const uint4*)(f2u + (size_t)d * KPU + cl); \
                    }                                                         \
                    fa[g][0] += bflo(cur.x); fa[g][1] += bfhi(cur.x);         \
                    fa[g][2] += bflo(cur.y); fa[g][3] += bfhi(cur.y);         \
                    fa[g][4] += bflo(cur.z); fa[g][5] += bfhi(cur.z);         \
                    fa[g][6] += bflo(cur.w); fa[g][7] += bfhi(cur.w);         \
                }                                                             \
            }                                                                 \
        }                                                                     \
        _Pragma("unroll")                                                     \
        for (int g = 0; g < 4; ++g) {                                         \
            const float inv = gcnt[g] ? 1.0f / (float)gcnt[g] : 0.f;          \
            if (lane < 38) {                                                  \
                uint2 w0, w1;                                                 \
                w0.x = packbf(fa[g][0] * inv, fa[g][1] * inv);                \
                w0.y = packbf(fa[g][2] * inv, fa[g][3] * inv);                \
                w1.x = packbf(fa[g][4] * inv, fa[g][5] * inv);                \
                w1.y = packbf(fa[g][6] * inv, fa[g][7] * inv);                \
                unsigned short* sp = &sbf[bb][(wave * 4 + g) * SBS + 8 * lane]; \
                *(uint2*)(sp)     = w0;                                       \
                *(uint2*)(sp + 4) = w1;                                       \
            }                                                                 \
        }                                                                     \
    }

    PROLOGUE(0);
    BODY(0);
    __syncthreads();

    int buf = 0;
    for (int r = 0; r < RR; ++r) {
        if (r + 1 < RR) PROLOGUE(r + 1);      // loads fly under the MFMA below

        const unsigned short* wb = wt + ((size_t)(r * OUTD + o0 + row) * KP) + 8 * q;
        const unsigned short* ab = &sbf[buf][row * SBS + 8 * q];
#pragma unroll
        for (int ks = 0; ks < 19; ++ks) {
            UA a; UB b;
            a.d[0] = *(const uint2*)(ab + 16 * ks);
            a.d[1] = *(const uint2*)(ab + 16 * ks + 4);
            b.q    = *(const uint4*)(wb + 16 * ks);
            acc = __builtin_amdgcn_mfma_f32_32x32x16_bf16(a.v, b.v, acc, 0, 0, 0);
        }

        if (r + 1 < RR) BODY(buf ^ 1);
        __syncthreads();
        buf ^= 1;
    }

    // --- epilogue: C/D layout col=lane&31 (=o), row=(reg&3)+8*(reg>>2)+4*q (=node)
    const int o = o0 + row;
    const float bv = bias[o];
#pragma unroll
    for (int reg = 0; reg < 16; ++reg) {
        const int node = (reg & 3) + 8 * (reg >> 2) + 4 * q;
        out[(size_t)(n0 + node) * OUTD + o] = acc[reg] + bv;
    }
#undef PROLOGUE
#undef BODY
}

extern "C" void kernel_launch(void* const* d_in, const int* in_sizes, int n_in,
                              void* d_out, int out_size, void* d_ws, size_t ws_size,
                              hipStream_t stream) {
    const float* feat  = (const float*)d_in[0];
    const float* comps = (const float*)d_in[1];
    const float* bases = (const float*)d_in[2];
    const float* bias  = (const float*)d_in[3];
    const int*   esrc  = (const int*)d_in[4];
    const int*   erel  = (const int*)d_in[5];
    const int*   edst  = (const int*)d_in[6];
    float* out = (float*)d_out;

    char* ws = (char*)d_ws;
    // ws layout (bytes):
    unsigned short* wt   = (unsigned short*)(ws + 0);        //  1,712,128
    unsigned*       hist = (unsigned*)(ws + 1712128);        //    880,000
    unsigned*       off  = (unsigned*)(ws + 2592128);        //    880,064 (incl pad)
    unsigned*       off2 = (unsigned*)(ws + 3472192);        //    880,000
    unsigned*       bsum = (unsigned*)(ws + 4352192);        //      1,024
    unsigned*       ssd  = (unsigned*)(ws + 4353216);        //  2,560,000
    unsigned*       f2u  = (unsigned*)(ws + 6913216);        // 12,160,000 -> 19,073,216

    hipLaunchKernelGGL(k_prep,    dim3(FB + WB + HB), dim3(256), 0, stream,
                       feat, comps, bases, f2u, wt, hist);
    hipLaunchKernelGGL(k_hist,    dim3(2500), dim3(256), 0, stream, esrc, erel, hist);
    hipLaunchKernelGGL(k_scan1,   dim3(NSCAN_BLOCKS), dim3(256), 0, stream, hist, off, bsum);
    hipLaunchKernelGGL(k_scan23,  dim3(860),  dim3(256), 0, stream, off, off2, bsum);
    hipLaunchKernelGGL(k_scatter, dim3(2500), dim3(256), 0, stream, esrc, erel, edst, off2, ssd);
    hipLaunchKernelGGL(k_main,    dim3(625),  dim3(512), 0, stream,
                       f2u, bias, off, ssd, wt, out);

    (void)in_sizes; (void)n_in; (void)out_size; (void)ws_size;
}

// Round 6
// 490.364 us; speedup vs baseline: 1.2080x; 1.2080x over previous
//
#include <hip/hip_runtime.h>

// Problem constants (fixed by reference)
#define NN   20000
#define RR   11
#define BB   8
#define IND  300
#define OUTD 256
#define EE   640000
#define RN   (RR * NN)      // 220000 buckets, key = rel*N + src
#define NSCAN_BLOCKS 215    // ceil(220000 / 1024)
// K partitioning: 4 planes of 76 (pad to 80 = 5 MFMA k-steps)
#define KQN  4
#define PLU  760000u        // uints per f2u plane (20000 * 38)
#define WTU  112640u        // uints per wt plane (11*256*40)
#define SBU  42             // sbf row stride in uints (84 bf16; 2-way banks = free)
#define PPL  5120000u       // floats per P plane (20000*256)
#define FB   5938           // k_prep blocks: feat convert (1,520,000 uint2 items)
#define WB   44             // k_prep blocks: wt tiles (11 r x 4 o-tiles)
#define HB   215            // k_prep blocks: hist zero

typedef short bf16x8 __attribute__((ext_vector_type(8)));
typedef float f32x16 __attribute__((ext_vector_type(16)));

union UA { bf16x8 v; uint2 d[2]; };
union UB { bf16x8 v; uint4 q; };

__device__ inline unsigned short f2bf(float f) {
    union { float f; unsigned u; } x;
    x.f = f;
    unsigned u = x.u;
    u += 0x7fffu + ((u >> 16) & 1u);   // round-to-nearest-even
    return (unsigned short)(u >> 16);
}
__device__ inline float bflo(unsigned p) { return __uint_as_float(p << 16); }
__device__ inline float bfhi(unsigned p) { return __uint_as_float(p & 0xFFFF0000u); }
__device__ inline unsigned packbf(float x, float y) {
    return (unsigned)f2bf(x) | ((unsigned)f2bf(y) << 16);
}

// ---- fused prep: feat->bf16 K-planes | wt K-plane tiles | hist zero
__global__ __launch_bounds__(256) void k_prep(const float* __restrict__ feat,
                                              const float* __restrict__ comps,
                                              const float* __restrict__ bases,
                                              unsigned* __restrict__ f2u,
                                              unsigned* __restrict__ wtu,
                                              unsigned* __restrict__ hist) {
    __shared__ unsigned short ld[304 * 65];   // wt tile (k x o), pad 65 -> conflict-free
    const int b = blockIdx.x, tid = threadIdx.x;

    if (b < FB) {
        // f2u[kq][d][38 uints]: plane kq holds bf16 pairs for k in [76kq, 76kq+76)
        const unsigned t = b * 256u + (unsigned)tid;
        if (t < 1520000u) {
            const unsigned d  = t / 76u, rem = t - d * 76u;
            const unsigned kq = rem / 19u, w2 = rem - kq * 19u;
            const unsigned k  = kq * 76u + w2 * 4u;
            uint2 o; o.x = 0u; o.y = 0u;
            if (k < 300u) {
                const float4 x = *(const float4*)(feat + (size_t)d * IND + k);
                o.x = packbf(x.x, x.y);
                o.y = packbf(x.z, x.w);
            }
            *(uint2*)(f2u + (size_t)kq * PLU + d * 38u + w2 * 2u) = o;
        }
        return;
    }
    if (b < FB + WB) {
        // wt[kq][r][o][40 uints]: coalesced bases reads, LDS transpose, plane writes
        const int w  = b - FB;               // 0..43
        const int r  = w >> 2, o0 = (w & 3) * 64;
        const int o4 = tid & 63, kq4 = tid >> 6;    // kq4 0..3
        float cw[BB];
#pragma unroll
        for (int bb = 0; bb < BB; ++bb) cw[bb] = comps[r * BB + bb];
        for (int ks = 0; ks < 76; ++ks) {
            const int k = ks * 4 + kq4;
            float acc = 0.f;
            if (k < IND) {
#pragma unroll
                for (int bb = 0; bb < BB; ++bb)
                    acc += cw[bb] * bases[((size_t)bb * IND + k) * OUTD + o0 + o4];
            }
            ld[k * 65 + o4] = f2bf(acc);
        }
        __syncthreads();
        for (int j = tid; j < 64 * 160; j += 256) {
            const int oo = j / 160, rem = j - oo * 160;
            const int kq = rem / 40, ku = rem - kq * 40;
            unsigned val = 0u;
            if (ku < 38) {
                const int gk = kq * 76 + 2 * ku;
                val = (unsigned)ld[gk * 65 + oo] | ((unsigned)ld[(gk + 1) * 65 + oo] << 16);
            }
            wtu[(size_t)kq * WTU + ((size_t)(r * OUTD + o0 + oo)) * 40u + ku] = val;
        }
        return;
    }
    // hist zero
    const unsigned base = (unsigned)(b - FB - WB) * 1024u + (unsigned)tid;
#pragma unroll
    for (int i = 0; i < 4; ++i) {
        const unsigned idx = base + i * 256u;
        if (idx < RN) hist[idx] = 0u;
    }
}

// ---------------------------------------------------------------- histogram
__global__ __launch_bounds__(256) void k_hist(const int* __restrict__ esrc,
                                              const int* __restrict__ erel,
                                              unsigned* __restrict__ hist) {
    const int e = blockIdx.x * 256 + threadIdx.x;           // exactly 640000
    const unsigned key = (unsigned)erel[e] * NN + (unsigned)esrc[e];
    atomicAdd(&hist[key], 1u);
}

// ------------------------------------------------- scan level 1 (1024/block)
__global__ __launch_bounds__(256) void k_scan1(const unsigned* __restrict__ hist,
                                               unsigned* __restrict__ off,
                                               unsigned* __restrict__ bsum) {
    __shared__ unsigned sc[256];
    const int tid = threadIdx.x;
    const unsigned base = blockIdx.x * 1024u + (unsigned)tid * 4u;
    unsigned v0 = (base + 0 < RN) ? hist[base + 0] : 0u;
    unsigned v1 = (base + 1 < RN) ? hist[base + 1] : 0u;
    unsigned v2 = (base + 2 < RN) ? hist[base + 2] : 0u;
    unsigned v3 = (base + 3 < RN) ? hist[base + 3] : 0u;
    const unsigned s = v0 + v1 + v2 + v3;
    sc[tid] = s;
    __syncthreads();
    for (int d = 1; d < 256; d <<= 1) {
        unsigned t = (tid >= d) ? sc[tid - d] : 0u;
        __syncthreads();
        sc[tid] += t;
        __syncthreads();
    }
    if (tid == 255) bsum[blockIdx.x] = sc[255];
    unsigned run = sc[tid] - s;                              // exclusive
    if (base + 0 < RN) off[base + 0] = run; run += v0;
    if (base + 1 < RN) off[base + 1] = run; run += v1;
    if (base + 2 < RN) off[base + 2] = run; run += v2;
    if (base + 3 < RN) off[base + 3] = run;
}

// ------------- scan levels 2+3 fused: every block re-scans bsum (tiny, L2)
__global__ __launch_bounds__(256) void k_scan23(unsigned* __restrict__ off,
                                                unsigned* __restrict__ off2,
                                                const unsigned* __restrict__ bsum) {
    __shared__ unsigned sb[256];
    const int tid = threadIdx.x;
    if (tid < 64) {
        unsigned v[4]; unsigned tot = 0;
#pragma unroll
        for (int i = 0; i < 4; ++i) {
            const int idx = tid * 4 + i;
            v[i] = (idx < NSCAN_BLOCKS) ? bsum[idx] : 0u;
            tot += v[i];
        }
        unsigned sc = tot;
        for (int d = 1; d < 64; d <<= 1) {
            unsigned t = __shfl_up(sc, d, 64);
            if (tid >= d) sc += t;
        }
        unsigned run = sc - tot;
#pragma unroll
        for (int i = 0; i < 4; ++i) {
            sb[tid * 4 + i] = run;
            run += v[i];
        }
    }
    __syncthreads();
    const unsigned idx = blockIdx.x * 256u + (unsigned)tid;
    if (idx < RN) {
        const unsigned v = off[idx] + sb[idx >> 10];
        off[idx]  = v;
        off2[idx] = v;
    }
    if (idx == 0) off[RN] = EE;
}

// ------------------------------------------------------- counting-sort scatter
__global__ __launch_bounds__(256) void k_scatter(const int* __restrict__ esrc,
                                                 const int* __restrict__ erel,
                                                 const int* __restrict__ edst,
                                                 unsigned* __restrict__ off2,
                                                 unsigned* __restrict__ ssd) {
    const int e = blockIdx.x * 256 + threadIdx.x;           // exactly 640000
    const unsigned key = (unsigned)erel[e] * NN + (unsigned)esrc[e];
    const unsigned p = atomicAdd(&off2[key], 1u);
    ssd[p] = (unsigned)edst[e];                              // dst only; src = bucket
}

// ---------------------------------------------------------------- fused main
// grid = tile*4 + kq (2500 blocks). Round-robin block->XCD dispatch pins each
// K-quarter plane (3.04 MB) to 2 XCDs -> gather becomes L2-resident.
// Per block: 32 nodes x K-slice 76(->80). Wave owns 4 nodes; lanes<38 own one
// bf16-pair column; depth-1 row prefetch; no LDS atomics; register-lean
// (R5's deep pipeline spilled: VGPR=64 + 450 MB scratch traffic).
// Epilogue: USEP -> K-partial into P plane (k_add reduces); else atomicAdd
// into bias-pre-initialized out.
template<int USEP>
__global__ __launch_bounds__(512, 8) void k_main(const unsigned* __restrict__ f2u,
                                                 const unsigned* __restrict__ offs,
                                                 const unsigned* __restrict__ ssd,
                                                 const unsigned* __restrict__ wtu,
                                                 float* __restrict__ out,
                                                 float* __restrict__ P) {
    __shared__ unsigned sbu[32 * SBU];        // A tile: 32 rows x 42 uints
    __shared__ unsigned soffs[RR * 33];

    const int tid  = threadIdx.x;
    const int wave = tid >> 6;
    const int lane = tid & 63;
    const int row  = lane & 31;
    const int q    = lane >> 5;
    const int kq   = blockIdx.x & 3;
    const int tile = blockIdx.x >> 2;
    const int n0   = tile * 32;
    const int o0   = wave * 32;

    const unsigned* fp = f2u + (size_t)kq * PLU;    // this block's K-plane
    const unsigned* wp = wtu + (size_t)kq * WTU;

    if (tid < RR * 33) {
        const int r = tid / 33, j = tid - r * 33;
        soffs[tid] = offs[r * NN + n0 + j];
    }

    f32x16 acc;
#pragma unroll
    for (int i = 0; i < 16; ++i) acc[i] = 0.f;

    __syncthreads();

    for (int r = 0; r < RR; ++r) {
        const unsigned* so = soffs + r * 33 + wave * 4;
#pragma unroll
        for (int g = 0; g < 4; ++g) {
            const unsigned c0 = so[g], c1 = so[g + 1];
            const unsigned cnt = c1 - c0;
            float a0 = 0.f, a1 = 0.f;
            // depth-1 software pipeline: row e+1 in flight while consuming row e
            unsigned vcur = 0u;
            if (cnt) {
                const unsigned d0 = ssd[c0];
                if (lane < 38) vcur = fp[d0 * 38u + (unsigned)lane];
            }
            for (unsigned e = 1; e < cnt; ++e) {
                const unsigned dn = ssd[c0 + e];
                unsigned vnx = 0u;
                if (lane < 38) vnx = fp[dn * 38u + (unsigned)lane];
                a0 += bflo(vcur); a1 += bfhi(vcur);
                vcur = vnx;
            }
            if (cnt) { a0 += bflo(vcur); a1 += bfhi(vcur); }
            const float inv = cnt ? 1.0f / (float)cnt : 0.f;
            if (lane < 40)
                sbu[(wave * 4 + g) * SBU + lane] =
                    (lane < 38) ? packbf(a0 * inv, a1 * inv) : 0u;
        }
        __syncthreads();

        // --- MFMA: C[32 nodes x 32 outs] += A[32 x 80] * B[80 x 32]
        const unsigned short* wb =
            (const unsigned short*)(wp + (size_t)(r * OUTD + o0 + row) * 40u) + 8 * q;
        const unsigned short* ab = (const unsigned short*)(sbu + row * SBU) + 8 * q;
#pragma unroll
        for (int ks = 0; ks < 5; ++ks) {
            UA a; UB b;
            a.d[0] = *(const uint2*)(ab + 16 * ks);
            a.d[1] = *(const uint2*)(ab + 16 * ks + 4);
            b.q    = *(const uint4*)(wb + 16 * ks);
            acc = __builtin_amdgcn_mfma_f32_32x32x16_bf16(a.v, b.v, acc, 0, 0, 0);
        }
        __syncthreads();
    }

    // --- epilogue: C/D layout col=lane&31 (=o), row=(reg&3)+8*(reg>>2)+4*q (=node)
    const int o = o0 + row;
    if (USEP) {
        float* op = P + (size_t)kq * PPL;
#pragma unroll
        for (int reg = 0; reg < 16; ++reg) {
            const int node = (reg & 3) + 8 * (reg >> 2) + 4 * q;
            op[(size_t)(n0 + node) * OUTD + o] = acc[reg];
        }
    } else {
#pragma unroll
        for (int reg = 0; reg < 16; ++reg) {
            const int node = (reg & 3) + 8 * (reg >> 2) + 4 * q;
            atomicAdd(&out[(size_t)(n0 + node) * OUTD + o], acc[reg]);
        }
    }
}

// ---------------- out = bias (atomic-fallback init), or out = sum(P) + bias
__global__ __launch_bounds__(256) void k_initout(float* __restrict__ out,
                                                 const float* __restrict__ bias) {
    const unsigned i = blockIdx.x * 256u + threadIdx.x;     // 1,280,000 float4
    ((float4*)out)[i] = ((const float4*)bias)[i & 63u];
}

__global__ __launch_bounds__(256) void k_add(float* __restrict__ out,
                                             const float* __restrict__ P,
                                             const float* __restrict__ bias) {
    const unsigned i = blockIdx.x * 256u + threadIdx.x;     // 1,280,000 float4
    const float4 p0 = ((const float4*)(P))[i];
    const float4 p1 = ((const float4*)(P + PPL))[i];
    const float4 p2 = ((const float4*)(P + 2 * (size_t)PPL))[i];
    const float4 p3 = ((const float4*)(P + 3 * (size_t)PPL))[i];
    const float4 bv = ((const float4*)bias)[i & 63u];
    float4 o;
    o.x = p0.x + p1.x + p2.x + p3.x + bv.x;
    o.y = p0.y + p1.y + p2.y + p3.y + bv.y;
    o.z = p0.z + p1.z + p2.z + p3.z + bv.z;
    o.w = p0.w + p1.w + p2.w + p3.w + bv.w;
    ((float4*)out)[i] = o;
}

extern "C" void kernel_launch(void* const* d_in, const int* in_sizes, int n_in,
                              void* d_out, int out_size, void* d_ws, size_t ws_size,
                              hipStream_t stream) {
    const float* feat  = (const float*)d_in[0];
    const float* comps = (const float*)d_in[1];
    const float* bases = (const float*)d_in[2];
    const float* bias  = (const float*)d_in[3];
    const int*   esrc  = (const int*)d_in[4];
    const int*   erel  = (const int*)d_in[5];
    const int*   edst  = (const int*)d_in[6];
    float* out = (float*)d_out;

    char* ws = (char*)d_ws;
    // ws layout (bytes):
    unsigned* wtu  = (unsigned*)(ws + 0);          //  1,802,240 (4 planes x 450,560)
    unsigned* hist = (unsigned*)(ws + 1802240);    //    880,000
    unsigned* off  = (unsigned*)(ws + 2682240);    //    880,064 (incl pad)
    unsigned* off2 = (unsigned*)(ws + 3562304);    //    880,000
    unsigned* bsum = (unsigned*)(ws + 4442304);    //      1,024
    unsigned* ssd  = (unsigned*)(ws + 4443328);    //  2,560,000
    unsigned* f2u  = (unsigned*)(ws + 7003328);    // 12,160,000 -> 19,163,328
    float*    P    = (float*)(ws + 19163328);      // 81,920,000 -> 101,083,328

    const bool usep = ws_size >= (size_t)101083328;  // host-uniform every call

    hipLaunchKernelGGL(k_prep,    dim3(FB + WB + HB), dim3(256), 0, stream,
                       feat, comps, bases, f2u, wtu, hist);
    hipLaunchKernelGGL(k_hist,    dim3(2500), dim3(256), 0, stream, esrc, erel, hist);
    hipLaunchKernelGGL(k_scan1,   dim3(NSCAN_BLOCKS), dim3(256), 0, stream, hist, off, bsum);
    hipLaunchKernelGGL(k_scan23,  dim3(860),  dim3(256), 0, stream, off, off2, bsum);
    hipLaunchKernelGGL(k_scatter, dim3(2500), dim3(256), 0, stream, esrc, erel, edst, off2, ssd);
    if (usep) {
        hipLaunchKernelGGL((k_main<1>), dim3(2500), dim3(512), 0, stream,
                           f2u, off, ssd, wtu, out, P);
        hipLaunchKernelGGL(k_add, dim3(5000), dim3(256), 0, stream, out, P, bias);
    } else {
        hipLaunchKernelGGL(k_initout, dim3(5000), dim3(256), 0, stream, out, bias);
        hipLaunchKernelGGL((k_main<0>), dim3(2500), dim3(512), 0, stream,
                           f2u, off, ssd, wtu, out, P);
    }

    (void)in_sizes; (void)n_in; (void)out_size; (void)ws_size;
}

// Round 7
// 438.842 us; speedup vs baseline: 1.3498x; 1.1174x over previous
//
#include <hip/hip_runtime.h>

// Problem constants (fixed by reference)
#define NN   20000
#define RR   11
#define BB   8
#define IND  300
#define OUTD 256
#define EE   640000
#define RN   (RR * NN)      // 220000 buckets, key = rel*N + src
#define NSCAN_BLOCKS 215    // ceil(220000 / 1024)
// K partitioning: 4 planes of 76 (pad to 80 = 5 MFMA k-steps)
#define PLU  760000u        // uints per f2u plane (20000 * 38)
#define WTU  112640u        // uints per wt plane (11*256*40)
#define SBU  42             // sbf row stride in uints (84 bf16; 2-way banks = free)
#define PPL  5120000u       // floats per P plane (20000*256)
#define FB   5938           // k_prep blocks: feat convert (1,520,000 uint2 items)
#define WB   44             // k_prep blocks: wt tiles (11 r x 4 o-tiles)
#define HB   215            // k_prep blocks: hist zero

typedef short bf16x8 __attribute__((ext_vector_type(8)));
typedef float f32x16 __attribute__((ext_vector_type(16)));

union UA { bf16x8 v; uint2 d[2]; };
union UB { bf16x8 v; uint4 q; };

__device__ inline unsigned short f2bf(float f) {
    union { float f; unsigned u; } x;
    x.f = f;
    unsigned u = x.u;
    u += 0x7fffu + ((u >> 16) & 1u);   // round-to-nearest-even
    return (unsigned short)(u >> 16);
}
__device__ inline float bflo(unsigned p) { return __uint_as_float(p << 16); }
__device__ inline float bfhi(unsigned p) { return __uint_as_float(p & 0xFFFF0000u); }
__device__ inline unsigned packbf(float x, float y) {
    return (unsigned)f2bf(x) | ((unsigned)f2bf(y) << 16);
}

// ---- fused prep: feat->bf16 K-planes | wt K-plane tiles | hist zero
__global__ __launch_bounds__(256) void k_prep(const float* __restrict__ feat,
                                              const float* __restrict__ comps,
                                              const float* __restrict__ bases,
                                              unsigned* __restrict__ f2u,
                                              unsigned* __restrict__ wtu,
                                              unsigned* __restrict__ hist) {
    __shared__ unsigned short ld[304 * 65];   // wt tile (k x o), pad 65 -> conflict-free
    const int b = blockIdx.x, tid = threadIdx.x;

    if (b < FB) {
        // f2u[kq][d][38 uints]: plane kq holds bf16 pairs for k in [76kq, 76kq+76)
        const unsigned t = b * 256u + (unsigned)tid;
        if (t < 1520000u) {
            const unsigned d  = t / 76u, rem = t - d * 76u;
            const unsigned kq = rem / 19u, w2 = rem - kq * 19u;
            const unsigned k  = kq * 76u + w2 * 4u;
            uint2 o; o.x = 0u; o.y = 0u;
            if (k < 300u) {
                const float4 x = *(const float4*)(feat + (size_t)d * IND + k);
                o.x = packbf(x.x, x.y);
                o.y = packbf(x.z, x.w);
            }
            *(uint2*)(f2u + (size_t)kq * PLU + d * 38u + w2 * 2u) = o;
        }
        return;
    }
    if (b < FB + WB) {
        // wt[kq][r][o][40 uints]: coalesced bases reads, LDS transpose, plane writes
        const int w  = b - FB;               // 0..43
        const int r  = w >> 2, o0 = (w & 3) * 64;
        const int o4 = tid & 63, kq4 = tid >> 6;    // kq4 0..3
        float cw[BB];
#pragma unroll
        for (int bb = 0; bb < BB; ++bb) cw[bb] = comps[r * BB + bb];
        for (int ks = 0; ks < 76; ++ks) {
            const int k = ks * 4 + kq4;
            float acc = 0.f;
            if (k < IND) {
#pragma unroll
                for (int bb = 0; bb < BB; ++bb)
                    acc += cw[bb] * bases[((size_t)bb * IND + k) * OUTD + o0 + o4];
            }
            ld[k * 65 + o4] = f2bf(acc);
        }
        __syncthreads();
        for (int j = tid; j < 64 * 160; j += 256) {
            const int oo = j / 160, rem = j - oo * 160;
            const int kq = rem / 40, ku = rem - kq * 40;
            unsigned val = 0u;
            if (ku < 38) {
                const int gk = kq * 76 + 2 * ku;
                val = (unsigned)ld[gk * 65 + oo] | ((unsigned)ld[(gk + 1) * 65 + oo] << 16);
            }
            wtu[(size_t)kq * WTU + ((size_t)(r * OUTD + o0 + oo)) * 40u + ku] = val;
        }
        return;
    }
    // hist zero
    const unsigned base = (unsigned)(b - FB - WB) * 1024u + (unsigned)tid;
#pragma unroll
    for (int i = 0; i < 4; ++i) {
        const unsigned idx = base + i * 256u;
        if (idx < RN) hist[idx] = 0u;
    }
}

// ---------------------------------------------------------------- histogram
__global__ __launch_bounds__(256) void k_hist(const int* __restrict__ esrc,
                                              const int* __restrict__ erel,
                                              unsigned* __restrict__ hist) {
    const int e = blockIdx.x * 256 + threadIdx.x;           // exactly 640000
    const unsigned key = (unsigned)erel[e] * NN + (unsigned)esrc[e];
    atomicAdd(&hist[key], 1u);
}

// ------------------------------------------------- scan level 1 (1024/block)
__global__ __launch_bounds__(256) void k_scan1(const unsigned* __restrict__ hist,
                                               unsigned* __restrict__ off,
                                               unsigned* __restrict__ bsum) {
    __shared__ unsigned sc[256];
    const int tid = threadIdx.x;
    const unsigned base = blockIdx.x * 1024u + (unsigned)tid * 4u;
    unsigned v0 = (base + 0 < RN) ? hist[base + 0] : 0u;
    unsigned v1 = (base + 1 < RN) ? hist[base + 1] : 0u;
    unsigned v2 = (base + 2 < RN) ? hist[base + 2] : 0u;
    unsigned v3 = (base + 3 < RN) ? hist[base + 3] : 0u;
    const unsigned s = v0 + v1 + v2 + v3;
    sc[tid] = s;
    __syncthreads();
    for (int d = 1; d < 256; d <<= 1) {
        unsigned t = (tid >= d) ? sc[tid - d] : 0u;
        __syncthreads();
        sc[tid] += t;
        __syncthreads();
    }
    if (tid == 255) bsum[blockIdx.x] = sc[255];
    unsigned run = sc[tid] - s;                              // exclusive
    if (base + 0 < RN) off[base + 0] = run; run += v0;
    if (base + 1 < RN) off[base + 1] = run; run += v1;
    if (base + 2 < RN) off[base + 2] = run; run += v2;
    if (base + 3 < RN) off[base + 3] = run;
}

// ------------- scan levels 2+3 fused: every block re-scans bsum (tiny, L2)
__global__ __launch_bounds__(256) void k_scan23(unsigned* __restrict__ off,
                                                unsigned* __restrict__ off2,
                                                const unsigned* __restrict__ bsum) {
    __shared__ unsigned sb[256];
    const int tid = threadIdx.x;
    if (tid < 64) {
        unsigned v[4]; unsigned tot = 0;
#pragma unroll
        for (int i = 0; i < 4; ++i) {
            const int idx = tid * 4 + i;
            v[i] = (idx < NSCAN_BLOCKS) ? bsum[idx] : 0u;
            tot += v[i];
        }
        unsigned sc = tot;
        for (int d = 1; d < 64; d <<= 1) {
            unsigned t = __shfl_up(sc, d, 64);
            if (tid >= d) sc += t;
        }
        unsigned run = sc - tot;
#pragma unroll
        for (int i = 0; i < 4; ++i) {
            sb[tid * 4 + i] = run;
            run += v[i];
        }
    }
    __syncthreads();
    const unsigned idx = blockIdx.x * 256u + (unsigned)tid;
    if (idx < RN) {
        const unsigned v = off[idx] + sb[idx >> 10];
        off[idx]  = v;
        off2[idx] = v;
    }
    if (idx == 0) off[RN] = EE;
}

// ------------------------------------------------------- counting-sort scatter
__global__ __launch_bounds__(256) void k_scatter(const int* __restrict__ esrc,
                                                 const int* __restrict__ erel,
                                                 const int* __restrict__ edst,
                                                 unsigned* __restrict__ off2,
                                                 unsigned* __restrict__ ssd) {
    const int e = blockIdx.x * 256 + threadIdx.x;           // exactly 640000
    const unsigned key = (unsigned)erel[e] * NN + (unsigned)esrc[e];
    const unsigned p = atomicAdd(&off2[key], 1u);
    ssd[p] = (unsigned)edst[e];                              // dst only; src = bucket
}

// ---------------------------------------------------------------- fused main
// grid = tile*4 + kq (2500 blocks): kq->XCD pinning keeps the 3 MB K-plane
// L2-resident (R6 verified: FETCH 165->52 MB). New in R7: the 4 groups' edge
// ranges per (wave, relation) are CONTIGUOUS in ssd -> one 64-wide window
// load + v_readlane replaces all per-edge ssd loads; row loads use a depth-2
// rotating prefetch round-robin across groups (~8 loads in flight/wave).
// Register-lean (~30 VGPR state) to stay under the (512,8) 64-reg cap —
// R5's 90-reg version spilled. sbu double-buffered -> 1 barrier/relation.
// Overflow (>64 edges per wave-relation) falls back to serial path.
template<int USEP>
__global__ __launch_bounds__(512, 8) void k_main(const unsigned* __restrict__ f2u,
                                                 const unsigned* __restrict__ offs,
                                                 const unsigned* __restrict__ ssd,
                                                 const unsigned* __restrict__ wtu,
                                                 float* __restrict__ out,
                                                 float* __restrict__ P) {
    __shared__ unsigned sbu[2][32 * SBU];     // A tile: 32 rows x 42 uints, dbuf
    __shared__ unsigned soffs[RR * 33];

    const int tid  = threadIdx.x;
    const int wave = tid >> 6;
    const int lane = tid & 63;
    const int row  = lane & 31;
    const int q    = lane >> 5;
    const int kq   = blockIdx.x & 3;
    const int tile = blockIdx.x >> 2;
    const int n0   = tile * 32;
    const int o0   = wave * 32;
    const unsigned vcl = (unsigned)(lane < 38 ? lane : 37);  // clamped col

    const unsigned* fp = f2u + (size_t)kq * PLU;    // this block's K-plane
    const unsigned* wp = wtu + (size_t)kq * WTU;

    if (tid < RR * 33) {
        const int r = tid / 33, j = tid - r * 33;
        soffs[tid] = offs[r * NN + n0 + j];
    }

    f32x16 acc;
#pragma unroll
    for (int i = 0; i < 16; ++i) acc[i] = 0.f;

    __syncthreads();

    int buf = 0;
    for (int r = 0; r < RR; ++r) {
        const unsigned* so = soffs + r * 33 + wave * 4;
        const unsigned s0 = so[0];
        unsigned off[5];
#pragma unroll
        for (int g = 0; g < 5; ++g) off[g] = so[g] - s0;
        const unsigned total = off[4];
        unsigned cmax = 0;
#pragma unroll
        for (int g = 0; g < 4; ++g) cmax = max(cmax, off[g + 1] - off[g]);

        float fa0[4] = {0.f, 0.f, 0.f, 0.f}, fa1[4] = {0.f, 0.f, 0.f, 0.f};

        if (total <= 64u) {
            // one coalesced window load covers all 4 groups' edges
            const unsigned win = ((unsigned)lane < total) ? ssd[s0 + (unsigned)lane] : 0u;
            unsigned pA[4], pB[4];
#pragma unroll
            for (int g = 0; g < 4; ++g) {
                const unsigned c = off[g + 1] - off[g];
                pA[g] = (c > 0) ? fp[(size_t)(unsigned)__builtin_amdgcn_readlane(
                                          (int)win, (int)off[g]) * 38u + vcl] : 0u;
                pB[g] = (c > 1) ? fp[(size_t)(unsigned)__builtin_amdgcn_readlane(
                                          (int)win, (int)(off[g] + 1)) * 38u + vcl] : 0u;
            }
            for (unsigned e = 0; e < cmax; e += 2) {
#pragma unroll
                for (int g = 0; g < 4; ++g) {
                    const unsigned c = off[g + 1] - off[g];
                    if (e < c) {
                        fa0[g] += bflo(pA[g]); fa1[g] += bfhi(pA[g]);
                        if (e + 2 < c)
                            pA[g] = fp[(size_t)(unsigned)__builtin_amdgcn_readlane(
                                            (int)win, (int)(off[g] + e + 2)) * 38u + vcl];
                    }
                }
#pragma unroll
                for (int g = 0; g < 4; ++g) {
                    const unsigned c = off[g + 1] - off[g];
                    if (e + 1 < c) {
                        fa0[g] += bflo(pB[g]); fa1[g] += bfhi(pB[g]);
                        if (e + 3 < c)
                            pB[g] = fp[(size_t)(unsigned)__builtin_amdgcn_readlane(
                                            (int)win, (int)(off[g] + e + 3)) * 38u + vcl];
                    }
                }
            }
        } else {
            // rare overflow: serial depth-1 (R6 path)
#pragma unroll
            for (int g = 0; g < 4; ++g) {
                const unsigned c0 = s0 + off[g], c1 = s0 + off[g + 1];
                for (unsigned e = c0; e < c1; ++e) {
                    const unsigned v = fp[(size_t)ssd[e] * 38u + vcl];
                    fa0[g] += bflo(v); fa1[g] += bfhi(v);
                }
            }
        }

        // writeback A-rows (lanes 38,39 = K-pad zeros)
#pragma unroll
        for (int g = 0; g < 4; ++g) {
            const unsigned c = off[g + 1] - off[g];
            const float inv = c ? 1.0f / (float)c : 0.f;
            if (lane < 40)
                sbu[buf][(wave * 4 + g) * SBU + lane] =
                    (lane < 38) ? packbf(fa0[g] * inv, fa1[g] * inv) : 0u;
        }
        __syncthreads();

        // --- MFMA: C[32 nodes x 32 outs] += A[32 x 80] * B[80 x 32]
        const unsigned short* wb =
            (const unsigned short*)(wp + (size_t)(r * OUTD + o0 + row) * 40u) + 8 * q;
        const unsigned short* ab = (const unsigned short*)(sbu[buf] + row * SBU) + 8 * q;
#pragma unroll
        for (int ks = 0; ks < 5; ++ks) {
            UA a; UB b;
            a.d[0] = *(const uint2*)(ab + 16 * ks);
            a.d[1] = *(const uint2*)(ab + 16 * ks + 4);
            b.q    = *(const uint4*)(wb + 16 * ks);
            acc = __builtin_amdgcn_mfma_f32_32x32x16_bf16(a.v, b.v, acc, 0, 0, 0);
        }
        buf ^= 1;   // next gather writes the other buffer; no post-MFMA barrier
    }

    // --- epilogue: C/D layout col=lane&31 (=o), row=(reg&3)+8*(reg>>2)+4*q (=node)
    const int o = o0 + row;
    if (USEP) {
        float* op = P + (size_t)kq * PPL;
#pragma unroll
        for (int reg = 0; reg < 16; ++reg) {
            const int node = (reg & 3) + 8 * (reg >> 2) + 4 * q;
            op[(size_t)(n0 + node) * OUTD + o] = acc[reg];
        }
    } else {
#pragma unroll
        for (int reg = 0; reg < 16; ++reg) {
            const int node = (reg & 3) + 8 * (reg >> 2) + 4 * q;
            atomicAdd(&out[(size_t)(n0 + node) * OUTD + o], acc[reg]);
        }
    }
}

// ---------------- out = bias (atomic-fallback init), or out = sum(P) + bias
__global__ __launch_bounds__(256) void k_initout(float* __restrict__ out,
                                                 const float* __restrict__ bias) {
    const unsigned i = blockIdx.x * 256u + threadIdx.x;     // 1,280,000 float4
    ((float4*)out)[i] = ((const float4*)bias)[i & 63u];
}

__global__ __launch_bounds__(256) void k_add(float* __restrict__ out,
                                             const float* __restrict__ P,
                                             const float* __restrict__ bias) {
    const unsigned i = blockIdx.x * 256u + threadIdx.x;     // 1,280,000 float4
    const float4 p0 = ((const float4*)(P))[i];
    const float4 p1 = ((const float4*)(P + PPL))[i];
    const float4 p2 = ((const float4*)(P + 2 * (size_t)PPL))[i];
    const float4 p3 = ((const float4*)(P + 3 * (size_t)PPL))[i];
    const float4 bv = ((const float4*)bias)[i & 63u];
    float4 o;
    o.x = p0.x + p1.x + p2.x + p3.x + bv.x;
    o.y = p0.y + p1.y + p2.y + p3.y + bv.y;
    o.z = p0.z + p1.z + p2.z + p3.z + bv.z;
    o.w = p0.w + p1.w + p2.w + p3.w + bv.w;
    ((float4*)out)[i] = o;
}

extern "C" void kernel_launch(void* const* d_in, const int* in_sizes, int n_in,
                              void* d_out, int out_size, void* d_ws, size_t ws_size,
                              hipStream_t stream) {
    const float* feat  = (const float*)d_in[0];
    const float* comps = (const float*)d_in[1];
    const float* bases = (const float*)d_in[2];
    const float* bias  = (const float*)d_in[3];
    const int*   esrc  = (const int*)d_in[4];
    const int*   erel  = (const int*)d_in[5];
    const int*   edst  = (const int*)d_in[6];
    float* out = (float*)d_out;

    char* ws = (char*)d_ws;
    // ws layout (bytes):
    unsigned* wtu  = (unsigned*)(ws + 0);          //  1,802,240 (4 planes x 450,560)
    unsigned* hist = (unsigned*)(ws + 1802240);    //    880,000
    unsigned* off  = (unsigned*)(ws + 2682240);    //    880,064 (incl pad)
    unsigned* off2 = (unsigned*)(ws + 3562304);    //    880,000
    unsigned* bsum = (unsigned*)(ws + 4442304);    //      1,024
    unsigned* ssd  = (unsigned*)(ws + 4443328);    //  2,560,000
    unsigned* f2u  = (unsigned*)(ws + 7003328);    // 12,160,000 -> 19,163,328
    float*    P    = (float*)(ws + 19163328);      // 81,920,000 -> 101,083,328

    const bool usep = ws_size >= (size_t)101083328;  // host-uniform every call

    hipLaunchKernelGGL(k_prep,    dim3(FB + WB + HB), dim3(256), 0, stream,
                       feat, comps, bases, f2u, wtu, hist);
    hipLaunchKernelGGL(k_hist,    dim3(2500), dim3(256), 0, stream, esrc, erel, hist);
    hipLaunchKernelGGL(k_scan1,   dim3(NSCAN_BLOCKS), dim3(256), 0, stream, hist, off, bsum);
    hipLaunchKernelGGL(k_scan23,  dim3(860),  dim3(256), 0, stream, off, off2, bsum);
    hipLaunchKernelGGL(k_scatter, dim3(2500), dim3(256), 0, stream, esrc, erel, edst, off2, ssd);
    if (usep) {
        hipLaunchKernelGGL((k_main<1>), dim3(2500), dim3(512), 0, stream,
                           f2u, off, ssd, wtu, out, P);
        hipLaunchKernelGGL(k_add, dim3(5000), dim3(256), 0, stream, out, P, bias);
    } else {
        hipLaunchKernelGGL(k_initout, dim3(5000), dim3(256), 0, stream, out, bias);
        hipLaunchKernelGGL((k_main<0>), dim3(2500), dim3(512), 0, stream,
                           f2u, off, ssd, wtu, out, P);
    }

    (void)in_sizes; (void)n_in; (void)out_size; (void)ws_size;
}